// Round 20
// baseline (246.717 us; speedup 1.0000x reference)
//
#include <hip/hip_runtime.h>
#include <hip/hip_bf16.h>

// Problem constants (match reference)
#define N_NODES 50000
#define N_EDGES 800000
#define IN_C 256
#define HID_C 128
#define OUT_C 64

#define N_BINS ((N_NODES + 127) / 128)    // 391 dst-bins of 128 nodes
#define N_TOT (N_EDGES + N_NODES)         // 850000

// Radix binning pass
#define RB_BLOCK 1024
#define RB_EPT 8
#define RB_CHUNK (RB_BLOCK * RB_EPT)      // 8192 edges per block
#define RB_GRID ((N_TOT + RB_CHUNK - 1) / RB_CHUNK)  // 104

typedef __attribute__((ext_vector_type(8))) short bf16x8;
typedef __attribute__((ext_vector_type(4))) float f32x4;
typedef __attribute__((ext_vector_type(2))) _Float16 f16x2;

__device__ __forceinline__ ushort f2bf(float f) {
    uint u = __float_as_uint(f);
    u += 0x7fff + ((u >> 16) & 1);   // round-to-nearest-even
    return (ushort)(u >> 16);
}
__device__ __forceinline__ float bf2f(ushort h) {
    return __uint_as_float(((uint)h) << 16);
}
// Pack one fp32 value into uint: bf16(hi)<<16 | bf16(residual lo)
__device__ __forceinline__ uint packhl(float v) {
    ushort h = f2bf(v);
    ushort l = f2bf(v - bf2f(h));
    return ((uint)h << 16) | (uint)l;
}

// ---------------------------------------------------------------------------
// Graph preprocessing (bin-centric, no per-node global atomics)
// ---------------------------------------------------------------------------

__global__ __launch_bounds__(256) void zero_binhist_kernel(int* __restrict__ binhist) {
    int i = blockIdx.x * 256 + threadIdx.x;
    if (i < N_BINS) binhist[i] = 0;
}

__global__ __launch_bounds__(256) void bin_hist_kernel(const int* __restrict__ dst,
                                                       int* __restrict__ binhist) {
    __shared__ int h[N_BINS];
    int t = threadIdx.x;
    for (int b = t; b < N_BINS; b += 256) h[b] = 0;
    __syncthreads();
    for (int i = blockIdx.x * 256 + t; i < N_EDGES; i += gridDim.x * 256)
        atomicAdd(&h[dst[i] >> 7], 1);
    __syncthreads();
    for (int b = t; b < N_BINS; b += 256)
        if (h[b]) atomicAdd(&binhist[b], h[b]);
}

__global__ __launch_bounds__(512) void bin_scan_kernel(const int* __restrict__ binhist,
                                                       int* __restrict__ bin_base,
                                                       int* __restrict__ bincur,
                                                       int* __restrict__ row_ptr) {
    __shared__ int s[512];
    int t = threadIdx.x;
    int v = 0;
    if (t < N_BINS) {
        int sl = (t == N_BINS - 1) ? (N_NODES - (N_BINS - 1) * 128) : 128;
        v = binhist[t] + sl;
    }
    s[t] = v;
    __syncthreads();
    for (int off = 1; off < 512; off <<= 1) {
        int x = s[t];
        int a = (t >= off) ? s[t - off] : 0;
        __syncthreads();
        s[t] = x + a;
        __syncthreads();
    }
    if (t < N_BINS) {
        bin_base[t] = s[t] - v;
        bincur[t] = 0;
    }
    if (t == N_BINS - 1) bin_base[N_BINS] = s[t];
    if (t == 0) row_ptr[N_NODES] = N_TOT;
}

__global__ __launch_bounds__(RB_BLOCK) void bin_scatter_kernel(
    const int* __restrict__ src, const int* __restrict__ dst,
    const int* __restrict__ bin_base, int* __restrict__ bincur,
    uint* __restrict__ binned) {
    __shared__ int hist[N_BINS];
    __shared__ int cur[N_BINS];
    const int t = threadIdx.x;
    for (int b = t; b < N_BINS; b += RB_BLOCK) hist[b] = 0;
    __syncthreads();

    uint pk[RB_EPT];
    int bn[RB_EPT];
    const int base = blockIdx.x * RB_CHUNK;
#pragma unroll
    for (int k = 0; k < RB_EPT; k++) {
        int i = base + k * RB_BLOCK + t;
        bn[k] = -1;
        if (i < N_TOT) {
            int s, d;
            if (i < N_EDGES) {
                s = src[i];
                d = dst[i];
            } else {
                s = d = i - N_EDGES;
            }
            pk[k] = (uint)s | ((uint)d << 16);
            bn[k] = d >> 7;
            atomicAdd(&hist[bn[k]], 1);
        }
    }
    __syncthreads();

    for (int b = t; b < N_BINS; b += RB_BLOCK) {
        int c = hist[b];
        int g0 = (c > 0) ? atomicAdd(&bincur[b], c) : 0;
        cur[b] = bin_base[b] + g0;
    }
    __syncthreads();

#pragma unroll
    for (int k = 0; k < RB_EPT; k++) {
        if (bn[k] >= 0) {
            int pos = atomicAdd(&cur[bn[k]], 1);
            binned[pos] = pk[k];
        }
    }
}

__global__ __launch_bounds__(256) void csr_build_kernel(const uint* __restrict__ binned,
                                                        const int* __restrict__ bin_base,
                                                        int* __restrict__ row_ptr,
                                                        float* __restrict__ dis,
                                                        ushort* __restrict__ csr_src) {
    __shared__ int hist[128];
    __shared__ int sc[256];
    __shared__ int exs[128];
    __shared__ int cur[128];
    const int b = blockIdx.x;
    const int t = threadIdx.x;
    const int start = bin_base[b];
    const int cnt = bin_base[b + 1] - start;
    const int nloc = min(128, N_NODES - b * 128);

    if (t < 128) hist[t] = 0;
    __syncthreads();
    for (int i = t; i < cnt; i += 256) {
        uint e = binned[start + i];
        atomicAdd(&hist[(e >> 16) & 127], 1);
    }
    __syncthreads();
    sc[t] = (t < 128) ? hist[t] : 0;
    __syncthreads();
    for (int off = 1; off < 128; off <<= 1) {
        int x = sc[t];
        int a = (t >= off) ? sc[t - off] : 0;
        __syncthreads();
        sc[t] = x + a;
        __syncthreads();
    }
    if (t < 128) {
        exs[t] = sc[t] - hist[t];
        cur[t] = 0;
    }
    __syncthreads();
    if (t < nloc) {
        row_ptr[b * 128 + t] = start + exs[t];
        dis[b * 128 + t] = rsqrtf((float)hist[t]);
    }
    for (int i = t; i < cnt; i += 256) {
        uint e = binned[start + i];
        int dl = (e >> 16) & 127;
        int pos = start + exs[dl] + atomicAdd(&cur[dl], 1);
        csr_src[pos] = (ushort)(e & 0xFFFFu);
    }
}

// ---------------------------------------------------------------------------
// Weight packing: all 5 matrices in ONE launch.
// ---------------------------------------------------------------------------

__device__ __forceinline__ void pack_w_body(const float* W, ushort* Ph, ushort* Pl,
                                            int K, int N, int bb, int lane) {
    int CT = N / 16;
    int ct = bb % CT;
    int kt = bb / CT;
    int lr = lane & 15, lg = lane >> 4;
    size_t base = ((size_t)bb * 64 + lane) * 8;
#pragma unroll
    for (int j = 0; j < 8; j++) {
        float w = W[(size_t)(kt * 32 + lg * 8 + j) * N + ct * 16 + lr];
        ushort h = f2bf(w);
        ushort lo = f2bf(w - bf2f(h));
        Ph[base + j] = h;
        Pl[base + j] = lo;
    }
}

__global__ __launch_bounds__(64) void pack_all_kernel(
    const float* __restrict__ projW, const float* __restrict__ W0,
    const float* __restrict__ W1, const float* __restrict__ W2,
    const float* __restrict__ outW,
    ushort* __restrict__ Pph, ushort* __restrict__ Ppl,
    ushort* __restrict__ P0h, ushort* __restrict__ P0l,
    ushort* __restrict__ P1h, ushort* __restrict__ P1l,
    ushort* __restrict__ P2h, ushort* __restrict__ P2l,
    ushort* __restrict__ Poh, ushort* __restrict__ Pol) {
    int b = blockIdx.x;
    int lane = threadIdx.x;
    if (b < 64) {
        pack_w_body(projW, Pph, Ppl, IN_C, HID_C, b, lane);
    } else if (b < 160) {
        int l = (b - 64) >> 5;
        int bb = (b - 64) & 31;
        const float* W = (l == 0) ? W0 : (l == 1) ? W1 : W2;
        ushort* Ph = (l == 0) ? P0h : (l == 1) ? P1h : P2h;
        ushort* Pl = (l == 0) ? P0l : (l == 1) ? P1l : P2l;
        pack_w_body(W, Ph, Pl, HID_C, HID_C, bb, lane);
    } else {
        pack_w_body(outW, Poh, Pol, HID_C, OUT_C, b - 160, lane);
    }
}

// ---------------------------------------------------------------------------
// Split-K projection GEMM: block = 512 thr = 8 waves over a 64x128 tile.
// Waves 0-3 compute K 0..127, waves 4-7 compute K 128..255 of the SAME tile
// (per-wave kt chain halves: 8 -> 4; wave count doubles: 3126 -> 6256).
// Half-1 waves dump acc to LDS; one barrier; half-0 waves add + pack + store
// (no extra HBM traffic). fp32 A, 3-term bf16 split, MT=2, depth-3 rotation.
// Grid 782. Out: hx[node][128] = packhl(sum + bias)
// ---------------------------------------------------------------------------

__global__ __launch_bounds__(512) void proj_gemm_splitk_kernel(
    const float* __restrict__ Af, const ushort* __restrict__ Wph,
    const ushort* __restrict__ Wpl, const float* __restrict__ bias,
    uint* __restrict__ Cx, int M) {
    constexpr int KTH = 4;   // kt iterations per K-half
    constexpr int MT = 2;
    constexpr int AD = 3;
    __shared__ float red[64][132];   // half-1 partials, +4 pad

    const int t = threadIdx.x;
    const int wid = t >> 6;          // 0..7
    const int kh = wid >> 2;         // K-half 0/1
    const int w4 = wid & 3;
    const int lane = t & 63;
    const int lr = lane & 15;
    const int lg = lane >> 4;
    const int wr = w4 >> 1;          // row-group
    const int wc = w4 & 1;           // col-half
    const int row_base = blockIdx.x * 64 + wr * 32;
    const int ct0 = wc * 4;
    const int k0 = kh * 128;         // this half's K offset (elements)

    f32x4 acc[MT][4];
#pragma unroll
    for (int mt = 0; mt < MT; mt++)
#pragma unroll
        for (int ct = 0; ct < 4; ct++) acc[mt][ct] = (f32x4){0.f, 0.f, 0.f, 0.f};

    int rr_[MT];
#pragma unroll
    for (int mt = 0; mt < MT; mt++) {
        int r = row_base + mt * 16 + lr;
        rr_[mt] = (r >= M) ? (M - 1) : r;
    }

    float4 va[AD][MT][2];
#pragma unroll
    for (int p = 0; p < AD; p++)
#pragma unroll
        for (int mt = 0; mt < MT; mt++) {
            const float* ap = &Af[(size_t)rr_[mt] * IN_C + k0 + p * 32 + lg * 8];
            va[p][mt][0] = *(const float4*)ap;
            va[p][mt][1] = *(const float4*)(ap + 4);
        }

#pragma unroll
    for (int kt = 0; kt < KTH; kt++) {
        const int ktg = kh * KTH + kt;   // global kt for W
        const ushort* bh = &Wph[((size_t)ktg * 8 + ct0) * 512 + (size_t)lane * 8];
        const ushort* bl = &Wpl[((size_t)ktg * 8 + ct0) * 512 + (size_t)lane * 8];
        bf16x8 bhv[4], blv[4];
#pragma unroll
        for (int ct = 0; ct < 4; ct++) {
            bhv[ct] = *(const bf16x8*)(bh + ct * 512);
            blv[ct] = *(const bf16x8*)(bl + ct * 512);
        }

        bf16x8 ah[MT], al[MT];
        const int cb = kt % AD;
#pragma unroll
        for (int mt = 0; mt < MT; mt++) {
            float av[8] = {va[cb][mt][0].x, va[cb][mt][0].y, va[cb][mt][0].z, va[cb][mt][0].w,
                           va[cb][mt][1].x, va[cb][mt][1].y, va[cb][mt][1].z, va[cb][mt][1].w};
#pragma unroll
            for (int j = 0; j < 8; j++) {
                ushort h = f2bf(av[j]);
                ushort lo = f2bf(av[j] - bf2f(h));
                ah[mt][j] = (short)h;
                al[mt][j] = (short)lo;
            }
        }
        if (kt + AD < KTH) {
#pragma unroll
            for (int mt = 0; mt < MT; mt++) {
                const float* ap = &Af[(size_t)rr_[mt] * IN_C + k0 + (kt + AD) * 32 + lg * 8];
                va[cb][mt][0] = *(const float4*)ap;
                va[cb][mt][1] = *(const float4*)(ap + 4);
            }
        }

#pragma unroll
        for (int mt = 0; mt < MT; mt++)
#pragma unroll
            for (int ct = 0; ct < 4; ct++) {
                acc[mt][ct] = __builtin_amdgcn_mfma_f32_16x16x32_bf16(ah[mt], bhv[ct], acc[mt][ct], 0, 0, 0);
                acc[mt][ct] = __builtin_amdgcn_mfma_f32_16x16x32_bf16(al[mt], bhv[ct], acc[mt][ct], 0, 0, 0);
                acc[mt][ct] = __builtin_amdgcn_mfma_f32_16x16x32_bf16(ah[mt], blv[ct], acc[mt][ct], 0, 0, 0);
            }
    }

    // Cross-half reduction through LDS
    if (kh == 1) {
#pragma unroll
        for (int mt = 0; mt < MT; mt++)
#pragma unroll
            for (int ct = 0; ct < 4; ct++)
#pragma unroll
                for (int j = 0; j < 4; j++) {
                    int rl = wr * 32 + mt * 16 + lg * 4 + j;
                    int c = (ct0 + ct) * 16 + lr;
                    red[rl][c] = acc[mt][ct][j];
                }
    }
    __syncthreads();
    if (kh == 0) {
#pragma unroll
        for (int mt = 0; mt < MT; mt++)
#pragma unroll
            for (int ct = 0; ct < 4; ct++)
#pragma unroll
                for (int j = 0; j < 4; j++) {
                    int rl = wr * 32 + mt * 16 + lg * 4 + j;
                    int rr = blockIdx.x * 64 + rl;
                    if (rr >= M) continue;
                    int c = (ct0 + ct) * 16 + lr;
                    float v = acc[mt][ct][j] + red[rl][c] + bias[c];
                    Cx[(size_t)rr * HID_C + c] = packhl(v);
                }
    }
}

// ---------------------------------------------------------------------------
// LDS-staged conv GEMM: K=128, N=128, packed-A (proven r17 shape).
// ---------------------------------------------------------------------------

__global__ __launch_bounds__(256) void conv_gemm_lds_kernel(
    const uint* __restrict__ Ax, const ushort* __restrict__ Wph,
    const ushort* __restrict__ Wpl, const float* __restrict__ disp,
    _Float16* __restrict__ Ch, int M) {
    constexpr int KT = 4;
    __shared__ uint As[64][132];   // 128 words + 4 pad

    const int t = threadIdx.x;
    const int r0 = blockIdx.x * 64;

#pragma unroll
    for (int i = 0; i < 8; i++) {
        int slot = i * 256 + t;
        int row = slot >> 5;
        int c16 = (slot & 31) << 2;
        int gr = r0 + row;
        if (gr >= M) gr = M - 1;
        uint4 v = *(const uint4*)&Ax[(size_t)gr * HID_C + c16];
        *(uint4*)&As[row][c16] = v;
    }
    __syncthreads();

    const int wid = t >> 6;
    const int lane = t & 63;
    const int lr = lane & 15;
    const int lg = lane >> 4;
    const int wr = wid >> 1;
    const int wc = wid & 1;
    const int ct0 = wc * 4;

    f32x4 acc[2][4];
#pragma unroll
    for (int mt = 0; mt < 2; mt++)
#pragma unroll
        for (int ct = 0; ct < 4; ct++) acc[mt][ct] = (f32x4){0.f, 0.f, 0.f, 0.f};

#pragma unroll
    for (int kt = 0; kt < KT; kt++) {
        const ushort* bh = &Wph[((size_t)kt * 8 + ct0) * 512 + (size_t)lane * 8];
        const ushort* bl = &Wpl[((size_t)kt * 8 + ct0) * 512 + (size_t)lane * 8];
        bf16x8 bhv[4], blv[4];
#pragma unroll
        for (int ct = 0; ct < 4; ct++) {
            bhv[ct] = *(const bf16x8*)(bh + ct * 512);
            blv[ct] = *(const bf16x8*)(bl + ct * 512);
        }

        bf16x8 ah[2], al[2];
#pragma unroll
        for (int mt = 0; mt < 2; mt++) {
            int row = wr * 32 + mt * 16 + lr;
            uint4 a0 = *(const uint4*)&As[row][kt * 32 + lg * 8];
            uint4 a1 = *(const uint4*)&As[row][kt * 32 + lg * 8 + 4];
            union { uint u[4]; bf16x8 v; } ch_, cl_;
            const uint* w0 = (const uint*)&a0;
            const uint* w1 = (const uint*)&a1;
#pragma unroll
            for (int j = 0; j < 4; j++) {
                uint u0 = (j < 2) ? w0[j * 2] : w1[(j - 2) * 2];
                uint u1 = (j < 2) ? w0[j * 2 + 1] : w1[(j - 2) * 2 + 1];
                ch_.u[j] = (u0 >> 16) | (u1 & 0xFFFF0000u);
                cl_.u[j] = (u0 & 0xFFFFu) | (u1 << 16);
            }
            ah[mt] = ch_.v;
            al[mt] = cl_.v;
        }

#pragma unroll
        for (int mt = 0; mt < 2; mt++)
#pragma unroll
            for (int ct = 0; ct < 4; ct++) {
                acc[mt][ct] = __builtin_amdgcn_mfma_f32_16x16x32_bf16(ah[mt], bhv[ct], acc[mt][ct], 0, 0, 0);
                acc[mt][ct] = __builtin_amdgcn_mfma_f32_16x16x32_bf16(al[mt], bhv[ct], acc[mt][ct], 0, 0, 0);
                acc[mt][ct] = __builtin_amdgcn_mfma_f32_16x16x32_bf16(ah[mt], blv[ct], acc[mt][ct], 0, 0, 0);
            }
    }

#pragma unroll
    for (int mt = 0; mt < 2; mt++)
#pragma unroll
        for (int ct = 0; ct < 4; ct++)
#pragma unroll
            for (int j = 0; j < 4; j++) {
                int rr = r0 + wr * 32 + mt * 16 + lg * 4 + j;
                if (rr >= M) continue;
                int c = (ct0 + ct) * 16 + lr;
                Ch[(size_t)rr * HID_C + c] = (_Float16)(acc[mt][ct][j] * disp[rr]);
            }
}

// ---------------------------------------------------------------------------
// LDS-staged out GEMM: K=128 packed-A, N=64 (r19 shape).
// ---------------------------------------------------------------------------

__global__ __launch_bounds__(128) void out_gemm_lds_kernel(
    const uint* __restrict__ Ax, const ushort* __restrict__ Wph,
    const ushort* __restrict__ Wpl, const float* __restrict__ bias,
    float* __restrict__ Cf, int M) {
    constexpr int KT = 4;
    __shared__ uint As[64][132];

    const int t = threadIdx.x;
    const int r0 = blockIdx.x * 64;

#pragma unroll
    for (int i = 0; i < 16; i++) {
        int slot = i * 128 + t;
        int row = slot >> 5;
        int c16 = (slot & 31) << 2;
        int gr = r0 + row;
        if (gr >= M) gr = M - 1;
        uint4 v = *(const uint4*)&Ax[(size_t)gr * HID_C + c16];
        *(uint4*)&As[row][c16] = v;
    }
    __syncthreads();

    const int wid = t >> 6;
    const int lane = t & 63;
    const int lr = lane & 15;
    const int lg = lane >> 4;

    f32x4 acc[2][4];
#pragma unroll
    for (int mt = 0; mt < 2; mt++)
#pragma unroll
        for (int ct = 0; ct < 4; ct++) acc[mt][ct] = (f32x4){0.f, 0.f, 0.f, 0.f};

#pragma unroll
    for (int kt = 0; kt < KT; kt++) {
        const ushort* bh = &Wph[(size_t)kt * 4 * 512 + (size_t)lane * 8];
        const ushort* bl = &Wpl[(size_t)kt * 4 * 512 + (size_t)lane * 8];
        bf16x8 bhv[4], blv[4];
#pragma unroll
        for (int ct = 0; ct < 4; ct++) {
            bhv[ct] = *(const bf16x8*)(bh + ct * 512);
            blv[ct] = *(const bf16x8*)(bl + ct * 512);
        }

        bf16x8 ah[2], al[2];
#pragma unroll
        for (int mt = 0; mt < 2; mt++) {
            int row = wid * 32 + mt * 16 + lr;
            uint4 a0 = *(const uint4*)&As[row][kt * 32 + lg * 8];
            uint4 a1 = *(const uint4*)&As[row][kt * 32 + lg * 8 + 4];
            union { uint u[4]; bf16x8 v; } ch_, cl_;
            const uint* w0 = (const uint*)&a0;
            const uint* w1 = (const uint*)&a1;
#pragma unroll
            for (int j = 0; j < 4; j++) {
                uint u0 = (j < 2) ? w0[j * 2] : w1[(j - 2) * 2];
                uint u1 = (j < 2) ? w0[j * 2 + 1] : w1[(j - 2) * 2 + 1];
                ch_.u[j] = (u0 >> 16) | (u1 & 0xFFFF0000u);
                cl_.u[j] = (u0 & 0xFFFFu) | (u1 << 16);
            }
            ah[mt] = ch_.v;
            al[mt] = cl_.v;
        }

#pragma unroll
        for (int mt = 0; mt < 2; mt++)
#pragma unroll
            for (int ct = 0; ct < 4; ct++) {
                acc[mt][ct] = __builtin_amdgcn_mfma_f32_16x16x32_bf16(ah[mt], bhv[ct], acc[mt][ct], 0, 0, 0);
                acc[mt][ct] = __builtin_amdgcn_mfma_f32_16x16x32_bf16(al[mt], bhv[ct], acc[mt][ct], 0, 0, 0);
                acc[mt][ct] = __builtin_amdgcn_mfma_f32_16x16x32_bf16(ah[mt], blv[ct], acc[mt][ct], 0, 0, 0);
            }
    }

#pragma unroll
    for (int mt = 0; mt < 2; mt++)
#pragma unroll
        for (int ct = 0; ct < 4; ct++)
#pragma unroll
            for (int j = 0; j < 4; j++) {
                int rr = r0 + wid * 32 + mt * 16 + lg * 4 + j;
                if (rr >= M) continue;
                int c = ct * 16 + lr;
                Cf[(size_t)rr * OUT_C + c] = acc[mt][ct][j] + bias[c];
            }
}

// ---------------------------------------------------------------------------
// CSR aggregation: wave = node, 64 lanes x f16x2 = full 128-ch fp16 row
// (256 B) per instruction, unroll-16 (64 lines in flight per wave).
// out = relu(dis[node]*sum + bias) -> packed uint (uint2/lane, 512 B/wave).
// ---------------------------------------------------------------------------

__global__ __launch_bounds__(256) void aggregate_kernel(const _Float16* __restrict__ g,
                                                        const int* __restrict__ row_ptr,
                                                        const ushort* __restrict__ csr_src,
                                                        const float* __restrict__ dis,
                                                        const float* __restrict__ bias,
                                                        uint* __restrict__ hx) {
    const int wid = threadIdx.x >> 6;
    const int lane = threadIdx.x & 63;
    const int node = blockIdx.x * 4 + wid;
    if (node >= N_NODES) return;
    const int c2 = lane * 2;

    const int s0 = row_ptr[node];
    const int s1 = row_ptr[node + 1];

    float ax = 0.f, ay = 0.f;
    int e = s0;
    for (; e + 16 <= s1; e += 16) {
        int idx[16];
#pragma unroll
        for (int j = 0; j < 16; j++) idx[j] = csr_src[e + j];
        f16x2 v[16];
#pragma unroll
        for (int j = 0; j < 16; j++)
            v[j] = *(const f16x2*)&g[(size_t)idx[j] * HID_C + c2];
        float sx = 0.f, sy = 0.f;
#pragma unroll
        for (int j = 0; j < 16; j++) {
            sx += (float)v[j].x;
            sy += (float)v[j].y;
        }
        ax += sx;
        ay += sy;
    }
    for (; e + 4 <= s1; e += 4) {
        int idx[4];
#pragma unroll
        for (int j = 0; j < 4; j++) idx[j] = csr_src[e + j];
        f16x2 v[4];
#pragma unroll
        for (int j = 0; j < 4; j++)
            v[j] = *(const f16x2*)&g[(size_t)idx[j] * HID_C + c2];
        ax += ((float)v[0].x + (float)v[1].x) + ((float)v[2].x + (float)v[3].x);
        ay += ((float)v[0].y + (float)v[1].y) + ((float)v[2].y + (float)v[3].y);
    }
    for (; e < s1; e++) {
        int i0 = csr_src[e];
        f16x2 v0 = *(const f16x2*)&g[(size_t)i0 * HID_C + c2];
        ax += (float)v0.x;
        ay += (float)v0.y;
    }

    const float dn = dis[node];
    float2 bb = *(const float2*)&bias[c2];
    float vx = fmaxf(dn * ax + bb.x, 0.f);
    float vy = fmaxf(dn * ay + bb.y, 0.f);
    uint2 w;
    w.x = packhl(vx);
    w.y = packhl(vy);
    *(uint2*)&hx[(size_t)node * HID_C + c2] = w;
}

// ---------------------------------------------------------------------------
// Launch
// ---------------------------------------------------------------------------

extern "C" void kernel_launch(void* const* d_in, const int* in_sizes, int n_in,
                              void* d_out, int out_size, void* d_ws, size_t ws_size,
                              hipStream_t stream) {
    const float* x       = (const float*)d_in[0];
    const int*   eidx    = (const int*)d_in[1];
    const float* proj_W  = (const float*)d_in[2];
    const float* proj_b  = (const float*)d_in[3];
    const float* conv_W0 = (const float*)d_in[4];
    const float* conv_b0 = (const float*)d_in[5];
    const float* conv_W1 = (const float*)d_in[6];
    const float* conv_b1 = (const float*)d_in[7];
    const float* conv_W2 = (const float*)d_in[8];
    const float* conv_b2 = (const float*)d_in[9];
    const float* out_W   = (const float*)d_in[10];
    const float* out_b   = (const float*)d_in[11];
    float* out = (float*)d_out;

    const int* src = eidx;
    const int* dst = eidx + N_EDGES;

    char* ws = (char*)d_ws;
    size_t off = 0;
    auto carve = [&](size_t bytes) {
        void* p = ws + off;
        off += (bytes + 255) & ~(size_t)255;
        return p;
    };
    int*    row_ptr  = (int*)carve((N_NODES + 1) * sizeof(int));
    ushort* csr_src  = (ushort*)carve((size_t)N_TOT * sizeof(ushort));
    uint*   binned   = (uint*)carve((size_t)N_TOT * sizeof(uint));
    int*    binhist  = (int*)carve(N_BINS * sizeof(int));
    int*    bin_base = (int*)carve((N_BINS + 1) * sizeof(int));
    int*    bincur   = (int*)carve(N_BINS * sizeof(int));
    float*  dis      = (float*)carve(N_NODES * sizeof(float));
    ushort* projPh = (ushort*)carve((size_t)IN_C * HID_C * sizeof(ushort));
    ushort* projPl = (ushort*)carve((size_t)IN_C * HID_C * sizeof(ushort));
    ushort* convPh[3], *convPl[3];
    for (int l = 0; l < 3; l++) {
        convPh[l] = (ushort*)carve((size_t)HID_C * HID_C * sizeof(ushort));
        convPl[l] = (ushort*)carve((size_t)HID_C * HID_C * sizeof(ushort));
    }
    ushort* outPh = (ushort*)carve((size_t)HID_C * OUT_C * sizeof(ushort));
    ushort* outPl = (ushort*)carve((size_t)HID_C * OUT_C * sizeof(ushort));
    uint*   hx = (uint*)carve((size_t)N_NODES * HID_C * sizeof(uint));
    _Float16* g = (_Float16*)carve((size_t)N_NODES * HID_C * sizeof(_Float16));

    // Graph preprocessing (bin-centric)
    zero_binhist_kernel<<<(N_BINS + 255) / 256, 256, 0, stream>>>(binhist);
    bin_hist_kernel<<<196, 256, 0, stream>>>(dst, binhist);
    bin_scan_kernel<<<1, 512, 0, stream>>>(binhist, bin_base, bincur, row_ptr);
    bin_scatter_kernel<<<RB_GRID, RB_BLOCK, 0, stream>>>(
        src, dst, bin_base, bincur, binned);
    csr_build_kernel<<<N_BINS, 256, 0, stream>>>(
        binned, bin_base, row_ptr, dis, csr_src);

    // Weight packing: one launch for all 5 matrices
    pack_all_kernel<<<176, 64, 0, stream>>>(proj_W, conv_W0, conv_W1, conv_W2, out_W,
                                            projPh, projPl,
                                            convPh[0], convPl[0],
                                            convPh[1], convPl[1],
                                            convPh[2], convPl[2],
                                            outPh, outPl);

    const int grid_n128 = (N_NODES + 63) / 64;    // 782
    const int agg_grid  = (N_NODES + 3) / 4;      // 12500

    // Projection: hx = pack(x @ proj_W + proj_b)  (intra-block split-K)
    proj_gemm_splitk_kernel<<<grid_n128, 512, 0, stream>>>(
        x, projPh, projPl, proj_b, hx, N_NODES);

    // 3 GCN layers (conv = LDS-staged GEMM)
    ushort* Wh_[3] = {convPh[0], convPh[1], convPh[2]};
    ushort* Wl_[3] = {convPl[0], convPl[1], convPl[2]};
    const float* bs_[3] = {conv_b0, conv_b1, conv_b2};
    for (int l = 0; l < 3; l++) {
        conv_gemm_lds_kernel<<<grid_n128, 256, 0, stream>>>(
            hx, Wh_[l], Wl_[l], dis, g, N_NODES);
        aggregate_kernel<<<agg_grid, 256, 0, stream>>>(
            g, row_ptr, csr_src, dis, bs_[l], hx);
    }

    // Output: out = h @ out_W + out_b (fp32, LDS-staged)
    out_gemm_lds_kernel<<<grid_n128, 128, 0, stream>>>(
        hx, outPh, outPl, out_b, out, N_NODES);
}

// Round 21
// 242.112 us; speedup vs baseline: 1.0190x; 1.0190x over previous
//
#include <hip/hip_runtime.h>
#include <hip/hip_bf16.h>

// Problem constants (match reference)
#define N_NODES 50000
#define N_EDGES 800000
#define IN_C 256
#define HID_C 128
#define OUT_C 64

#define N_BINS ((N_NODES + 127) / 128)    // 391 dst-bins of 128 nodes
#define N_TOT (N_EDGES + N_NODES)         // 850000

// Radix binning pass
#define RB_BLOCK 1024
#define RB_EPT 8
#define RB_CHUNK (RB_BLOCK * RB_EPT)      // 8192 edges per block
#define RB_GRID ((N_TOT + RB_CHUNK - 1) / RB_CHUNK)  // 104

typedef __attribute__((ext_vector_type(8))) short bf16x8;
typedef __attribute__((ext_vector_type(4))) float f32x4;
typedef __attribute__((ext_vector_type(2))) _Float16 f16x2;

__device__ __forceinline__ ushort f2bf(float f) {
    uint u = __float_as_uint(f);
    u += 0x7fff + ((u >> 16) & 1);   // round-to-nearest-even
    return (ushort)(u >> 16);
}
__device__ __forceinline__ float bf2f(ushort h) {
    return __uint_as_float(((uint)h) << 16);
}
// Pack one fp32 value into uint: bf16(hi)<<16 | bf16(residual lo)
__device__ __forceinline__ uint packhl(float v) {
    ushort h = f2bf(v);
    ushort l = f2bf(v - bf2f(h));
    return ((uint)h << 16) | (uint)l;
}

// ---------------------------------------------------------------------------
// Graph preprocessing (bin-centric, no per-node global atomics)
// ---------------------------------------------------------------------------

__global__ __launch_bounds__(256) void zero_binhist_kernel(int* __restrict__ binhist) {
    int i = blockIdx.x * 256 + threadIdx.x;
    if (i < N_BINS) binhist[i] = 0;
}

__global__ __launch_bounds__(256) void bin_hist_kernel(const int* __restrict__ dst,
                                                       int* __restrict__ binhist) {
    __shared__ int h[N_BINS];
    int t = threadIdx.x;
    for (int b = t; b < N_BINS; b += 256) h[b] = 0;
    __syncthreads();
    for (int i = blockIdx.x * 256 + t; i < N_EDGES; i += gridDim.x * 256)
        atomicAdd(&h[dst[i] >> 7], 1);
    __syncthreads();
    for (int b = t; b < N_BINS; b += 256)
        if (h[b]) atomicAdd(&binhist[b], h[b]);
}

__global__ __launch_bounds__(512) void bin_scan_kernel(const int* __restrict__ binhist,
                                                       int* __restrict__ bin_base,
                                                       int* __restrict__ bincur,
                                                       int* __restrict__ row_ptr) {
    __shared__ int s[512];
    int t = threadIdx.x;
    int v = 0;
    if (t < N_BINS) {
        int sl = (t == N_BINS - 1) ? (N_NODES - (N_BINS - 1) * 128) : 128;
        v = binhist[t] + sl;
    }
    s[t] = v;
    __syncthreads();
    for (int off = 1; off < 512; off <<= 1) {
        int x = s[t];
        int a = (t >= off) ? s[t - off] : 0;
        __syncthreads();
        s[t] = x + a;
        __syncthreads();
    }
    if (t < N_BINS) {
        bin_base[t] = s[t] - v;
        bincur[t] = 0;
    }
    if (t == N_BINS - 1) bin_base[N_BINS] = s[t];
    if (t == 0) row_ptr[N_NODES] = N_TOT;
}

__global__ __launch_bounds__(RB_BLOCK) void bin_scatter_kernel(
    const int* __restrict__ src, const int* __restrict__ dst,
    const int* __restrict__ bin_base, int* __restrict__ bincur,
    uint* __restrict__ binned) {
    __shared__ int hist[N_BINS];
    __shared__ int cur[N_BINS];
    const int t = threadIdx.x;
    for (int b = t; b < N_BINS; b += RB_BLOCK) hist[b] = 0;
    __syncthreads();

    uint pk[RB_EPT];
    int bn[RB_EPT];
    const int base = blockIdx.x * RB_CHUNK;
#pragma unroll
    for (int k = 0; k < RB_EPT; k++) {
        int i = base + k * RB_BLOCK + t;
        bn[k] = -1;
        if (i < N_TOT) {
            int s, d;
            if (i < N_EDGES) {
                s = src[i];
                d = dst[i];
            } else {
                s = d = i - N_EDGES;
            }
            pk[k] = (uint)s | ((uint)d << 16);
            bn[k] = d >> 7;
            atomicAdd(&hist[bn[k]], 1);
        }
    }
    __syncthreads();

    for (int b = t; b < N_BINS; b += RB_BLOCK) {
        int c = hist[b];
        int g0 = (c > 0) ? atomicAdd(&bincur[b], c) : 0;
        cur[b] = bin_base[b] + g0;
    }
    __syncthreads();

#pragma unroll
    for (int k = 0; k < RB_EPT; k++) {
        if (bn[k] >= 0) {
            int pos = atomicAdd(&cur[bn[k]], 1);
            binned[pos] = pk[k];
        }
    }
}

__global__ __launch_bounds__(256) void csr_build_kernel(const uint* __restrict__ binned,
                                                        const int* __restrict__ bin_base,
                                                        int* __restrict__ row_ptr,
                                                        float* __restrict__ dis,
                                                        ushort* __restrict__ csr_src) {
    __shared__ int hist[128];
    __shared__ int sc[256];
    __shared__ int exs[128];
    __shared__ int cur[128];
    const int b = blockIdx.x;
    const int t = threadIdx.x;
    const int start = bin_base[b];
    const int cnt = bin_base[b + 1] - start;
    const int nloc = min(128, N_NODES - b * 128);

    if (t < 128) hist[t] = 0;
    __syncthreads();
    for (int i = t; i < cnt; i += 256) {
        uint e = binned[start + i];
        atomicAdd(&hist[(e >> 16) & 127], 1);
    }
    __syncthreads();
    sc[t] = (t < 128) ? hist[t] : 0;
    __syncthreads();
    for (int off = 1; off < 128; off <<= 1) {
        int x = sc[t];
        int a = (t >= off) ? sc[t - off] : 0;
        __syncthreads();
        sc[t] = x + a;
        __syncthreads();
    }
    if (t < 128) {
        exs[t] = sc[t] - hist[t];
        cur[t] = 0;
    }
    __syncthreads();
    if (t < nloc) {
        row_ptr[b * 128 + t] = start + exs[t];
        dis[b * 128 + t] = rsqrtf((float)hist[t]);
    }
    for (int i = t; i < cnt; i += 256) {
        uint e = binned[start + i];
        int dl = (e >> 16) & 127;
        int pos = start + exs[dl] + atomicAdd(&cur[dl], 1);
        csr_src[pos] = (ushort)(e & 0xFFFFu);
    }
}

// ---------------------------------------------------------------------------
// Weight packing: all 5 matrices in ONE launch.
// ---------------------------------------------------------------------------

__device__ __forceinline__ void pack_w_body(const float* W, ushort* Ph, ushort* Pl,
                                            int K, int N, int bb, int lane) {
    int CT = N / 16;
    int ct = bb % CT;
    int kt = bb / CT;
    int lr = lane & 15, lg = lane >> 4;
    size_t base = ((size_t)bb * 64 + lane) * 8;
#pragma unroll
    for (int j = 0; j < 8; j++) {
        float w = W[(size_t)(kt * 32 + lg * 8 + j) * N + ct * 16 + lr];
        ushort h = f2bf(w);
        ushort lo = f2bf(w - bf2f(h));
        Ph[base + j] = h;
        Pl[base + j] = lo;
    }
}

__global__ __launch_bounds__(64) void pack_all_kernel(
    const float* __restrict__ projW, const float* __restrict__ W0,
    const float* __restrict__ W1, const float* __restrict__ W2,
    const float* __restrict__ outW,
    ushort* __restrict__ Pph, ushort* __restrict__ Ppl,
    ushort* __restrict__ P0h, ushort* __restrict__ P0l,
    ushort* __restrict__ P1h, ushort* __restrict__ P1l,
    ushort* __restrict__ P2h, ushort* __restrict__ P2l,
    ushort* __restrict__ Poh, ushort* __restrict__ Pol) {
    int b = blockIdx.x;
    int lane = threadIdx.x;
    if (b < 64) {
        pack_w_body(projW, Pph, Ppl, IN_C, HID_C, b, lane);
    } else if (b < 160) {
        int l = (b - 64) >> 5;
        int bb = (b - 64) & 31;
        const float* W = (l == 0) ? W0 : (l == 1) ? W1 : W2;
        ushort* Ph = (l == 0) ? P0h : (l == 1) ? P1h : P2h;
        ushort* Pl = (l == 0) ? P0l : (l == 1) ? P1l : P2l;
        pack_w_body(W, Ph, Pl, HID_C, HID_C, bb, lane);
    } else {
        pack_w_body(outW, Poh, Pol, HID_C, OUT_C, b - 160, lane);
    }
}

// ---------------------------------------------------------------------------
// Register MFMA GEMM for the projection (r16/r19 proven shape): fp32 A,
// depth-3 rotation, MT=2, 3-term bf16 split. OUT: packed uint + bias.
// Block = 64 rows (2 row-groups x 2 col-halves); grid 782.
// ---------------------------------------------------------------------------

__global__ __launch_bounds__(256) void proj_gemm_kernel(
    const float* __restrict__ Af, const ushort* __restrict__ Wph,
    const ushort* __restrict__ Wpl, const float* __restrict__ bias,
    uint* __restrict__ Cx, int M) {
    constexpr int KT = IN_C / 32;   // 8
    constexpr int MT = 2;
    constexpr int AD = 3;

    const int wid = threadIdx.x >> 6;
    const int lane = threadIdx.x & 63;
    const int lr = lane & 15;
    const int lg = lane >> 4;
    const int wr = wid >> 1;
    const int wc = wid & 1;
    const int row_base = blockIdx.x * 64 + wr * 32;
    const int ct0 = wc * 4;

    f32x4 acc[MT][4];
#pragma unroll
    for (int mt = 0; mt < MT; mt++)
#pragma unroll
        for (int ct = 0; ct < 4; ct++) acc[mt][ct] = (f32x4){0.f, 0.f, 0.f, 0.f};

    int rr_[MT];
#pragma unroll
    for (int mt = 0; mt < MT; mt++) {
        int r = row_base + mt * 16 + lr;
        rr_[mt] = (r >= M) ? (M - 1) : r;
    }

    float4 va[AD][MT][2];
#pragma unroll
    for (int p = 0; p < AD; p++)
#pragma unroll
        for (int mt = 0; mt < MT; mt++) {
            const float* ap = &Af[(size_t)rr_[mt] * IN_C + p * 32 + lg * 8];
            va[p][mt][0] = *(const float4*)ap;
            va[p][mt][1] = *(const float4*)(ap + 4);
        }

#pragma unroll
    for (int kt = 0; kt < KT; kt++) {
        const ushort* bh = &Wph[((size_t)kt * 8 + ct0) * 512 + (size_t)lane * 8];
        const ushort* bl = &Wpl[((size_t)kt * 8 + ct0) * 512 + (size_t)lane * 8];
        bf16x8 bhv[4], blv[4];
#pragma unroll
        for (int ct = 0; ct < 4; ct++) {
            bhv[ct] = *(const bf16x8*)(bh + ct * 512);
            blv[ct] = *(const bf16x8*)(bl + ct * 512);
        }

        bf16x8 ah[MT], al[MT];
        const int cb = kt % AD;
#pragma unroll
        for (int mt = 0; mt < MT; mt++) {
            float av[8] = {va[cb][mt][0].x, va[cb][mt][0].y, va[cb][mt][0].z, va[cb][mt][0].w,
                           va[cb][mt][1].x, va[cb][mt][1].y, va[cb][mt][1].z, va[cb][mt][1].w};
#pragma unroll
            for (int j = 0; j < 8; j++) {
                ushort h = f2bf(av[j]);
                ushort lo = f2bf(av[j] - bf2f(h));
                ah[mt][j] = (short)h;
                al[mt][j] = (short)lo;
            }
        }
        if (kt + AD < KT) {
#pragma unroll
            for (int mt = 0; mt < MT; mt++) {
                const float* ap = &Af[(size_t)rr_[mt] * IN_C + (kt + AD) * 32 + lg * 8];
                va[cb][mt][0] = *(const float4*)ap;
                va[cb][mt][1] = *(const float4*)(ap + 4);
            }
        }

#pragma unroll
        for (int mt = 0; mt < MT; mt++)
#pragma unroll
            for (int ct = 0; ct < 4; ct++) {
                acc[mt][ct] = __builtin_amdgcn_mfma_f32_16x16x32_bf16(ah[mt], bhv[ct], acc[mt][ct], 0, 0, 0);
                acc[mt][ct] = __builtin_amdgcn_mfma_f32_16x16x32_bf16(al[mt], bhv[ct], acc[mt][ct], 0, 0, 0);
                acc[mt][ct] = __builtin_amdgcn_mfma_f32_16x16x32_bf16(ah[mt], blv[ct], acc[mt][ct], 0, 0, 0);
            }
    }

#pragma unroll
    for (int mt = 0; mt < MT; mt++)
#pragma unroll
        for (int ct = 0; ct < 4; ct++)
#pragma unroll
            for (int j = 0; j < 4; j++) {
                int rr = row_base + mt * 16 + lg * 4 + j;
                if (rr >= M) continue;
                int c = (ct0 + ct) * 16 + lr;
                Cx[(size_t)rr * HID_C + c] = packhl(acc[mt][ct][j] + bias[c]);
            }
}

// ---------------------------------------------------------------------------
// LDS-staged conv GEMM: K=128, N=128, packed-A (proven r17 shape).
// ---------------------------------------------------------------------------

__global__ __launch_bounds__(256) void conv_gemm_lds_kernel(
    const uint* __restrict__ Ax, const ushort* __restrict__ Wph,
    const ushort* __restrict__ Wpl, const float* __restrict__ disp,
    _Float16* __restrict__ Ch, int M) {
    constexpr int KT = 4;
    __shared__ uint As[64][132];   // 128 words + 4 pad

    const int t = threadIdx.x;
    const int r0 = blockIdx.x * 64;

#pragma unroll
    for (int i = 0; i < 8; i++) {
        int slot = i * 256 + t;
        int row = slot >> 5;
        int c16 = (slot & 31) << 2;
        int gr = r0 + row;
        if (gr >= M) gr = M - 1;
        uint4 v = *(const uint4*)&Ax[(size_t)gr * HID_C + c16];
        *(uint4*)&As[row][c16] = v;
    }
    __syncthreads();

    const int wid = t >> 6;
    const int lane = t & 63;
    const int lr = lane & 15;
    const int lg = lane >> 4;
    const int wr = wid >> 1;
    const int wc = wid & 1;
    const int ct0 = wc * 4;

    f32x4 acc[2][4];
#pragma unroll
    for (int mt = 0; mt < 2; mt++)
#pragma unroll
        for (int ct = 0; ct < 4; ct++) acc[mt][ct] = (f32x4){0.f, 0.f, 0.f, 0.f};

#pragma unroll
    for (int kt = 0; kt < KT; kt++) {
        const ushort* bh = &Wph[((size_t)kt * 8 + ct0) * 512 + (size_t)lane * 8];
        const ushort* bl = &Wpl[((size_t)kt * 8 + ct0) * 512 + (size_t)lane * 8];
        bf16x8 bhv[4], blv[4];
#pragma unroll
        for (int ct = 0; ct < 4; ct++) {
            bhv[ct] = *(const bf16x8*)(bh + ct * 512);
            blv[ct] = *(const bf16x8*)(bl + ct * 512);
        }

        bf16x8 ah[2], al[2];
#pragma unroll
        for (int mt = 0; mt < 2; mt++) {
            int row = wr * 32 + mt * 16 + lr;
            uint4 a0 = *(const uint4*)&As[row][kt * 32 + lg * 8];
            uint4 a1 = *(const uint4*)&As[row][kt * 32 + lg * 8 + 4];
            union { uint u[4]; bf16x8 v; } ch_, cl_;
            const uint* w0 = (const uint*)&a0;
            const uint* w1 = (const uint*)&a1;
#pragma unroll
            for (int j = 0; j < 4; j++) {
                uint u0 = (j < 2) ? w0[j * 2] : w1[(j - 2) * 2];
                uint u1 = (j < 2) ? w0[j * 2 + 1] : w1[(j - 2) * 2 + 1];
                ch_.u[j] = (u0 >> 16) | (u1 & 0xFFFF0000u);
                cl_.u[j] = (u0 & 0xFFFFu) | (u1 << 16);
            }
            ah[mt] = ch_.v;
            al[mt] = cl_.v;
        }

#pragma unroll
        for (int mt = 0; mt < 2; mt++)
#pragma unroll
            for (int ct = 0; ct < 4; ct++) {
                acc[mt][ct] = __builtin_amdgcn_mfma_f32_16x16x32_bf16(ah[mt], bhv[ct], acc[mt][ct], 0, 0, 0);
                acc[mt][ct] = __builtin_amdgcn_mfma_f32_16x16x32_bf16(al[mt], bhv[ct], acc[mt][ct], 0, 0, 0);
                acc[mt][ct] = __builtin_amdgcn_mfma_f32_16x16x32_bf16(ah[mt], blv[ct], acc[mt][ct], 0, 0, 0);
            }
    }

#pragma unroll
    for (int mt = 0; mt < 2; mt++)
#pragma unroll
        for (int ct = 0; ct < 4; ct++)
#pragma unroll
            for (int j = 0; j < 4; j++) {
                int rr = r0 + wr * 32 + mt * 16 + lg * 4 + j;
                if (rr >= M) continue;
                int c = (ct0 + ct) * 16 + lr;
                Ch[(size_t)rr * HID_C + c] = (_Float16)(acc[mt][ct][j] * disp[rr]);
            }
}

// ---------------------------------------------------------------------------
// LDS-staged out GEMM: K=128 packed-A, N=64 (r19 shape).
// ---------------------------------------------------------------------------

__global__ __launch_bounds__(128) void out_gemm_lds_kernel(
    const uint* __restrict__ Ax, const ushort* __restrict__ Wph,
    const ushort* __restrict__ Wpl, const float* __restrict__ bias,
    float* __restrict__ Cf, int M) {
    constexpr int KT = 4;
    __shared__ uint As[64][132];

    const int t = threadIdx.x;
    const int r0 = blockIdx.x * 64;

#pragma unroll
    for (int i = 0; i < 16; i++) {
        int slot = i * 128 + t;
        int row = slot >> 5;
        int c16 = (slot & 31) << 2;
        int gr = r0 + row;
        if (gr >= M) gr = M - 1;
        uint4 v = *(const uint4*)&Ax[(size_t)gr * HID_C + c16];
        *(uint4*)&As[row][c16] = v;
    }
    __syncthreads();

    const int wid = t >> 6;
    const int lane = t & 63;
    const int lr = lane & 15;
    const int lg = lane >> 4;

    f32x4 acc[2][4];
#pragma unroll
    for (int mt = 0; mt < 2; mt++)
#pragma unroll
        for (int ct = 0; ct < 4; ct++) acc[mt][ct] = (f32x4){0.f, 0.f, 0.f, 0.f};

#pragma unroll
    for (int kt = 0; kt < KT; kt++) {
        const ushort* bh = &Wph[(size_t)kt * 4 * 512 + (size_t)lane * 8];
        const ushort* bl = &Wpl[(size_t)kt * 4 * 512 + (size_t)lane * 8];
        bf16x8 bhv[4], blv[4];
#pragma unroll
        for (int ct = 0; ct < 4; ct++) {
            bhv[ct] = *(const bf16x8*)(bh + ct * 512);
            blv[ct] = *(const bf16x8*)(bl + ct * 512);
        }

        bf16x8 ah[2], al[2];
#pragma unroll
        for (int mt = 0; mt < 2; mt++) {
            int row = wid * 32 + mt * 16 + lr;
            uint4 a0 = *(const uint4*)&As[row][kt * 32 + lg * 8];
            uint4 a1 = *(const uint4*)&As[row][kt * 32 + lg * 8 + 4];
            union { uint u[4]; bf16x8 v; } ch_, cl_;
            const uint* w0 = (const uint*)&a0;
            const uint* w1 = (const uint*)&a1;
#pragma unroll
            for (int j = 0; j < 4; j++) {
                uint u0 = (j < 2) ? w0[j * 2] : w1[(j - 2) * 2];
                uint u1 = (j < 2) ? w0[j * 2 + 1] : w1[(j - 2) * 2 + 1];
                ch_.u[j] = (u0 >> 16) | (u1 & 0xFFFF0000u);
                cl_.u[j] = (u0 & 0xFFFFu) | (u1 << 16);
            }
            ah[mt] = ch_.v;
            al[mt] = cl_.v;
        }

#pragma unroll
        for (int mt = 0; mt < 2; mt++)
#pragma unroll
            for (int ct = 0; ct < 4; ct++) {
                acc[mt][ct] = __builtin_amdgcn_mfma_f32_16x16x32_bf16(ah[mt], bhv[ct], acc[mt][ct], 0, 0, 0);
                acc[mt][ct] = __builtin_amdgcn_mfma_f32_16x16x32_bf16(al[mt], bhv[ct], acc[mt][ct], 0, 0, 0);
                acc[mt][ct] = __builtin_amdgcn_mfma_f32_16x16x32_bf16(ah[mt], blv[ct], acc[mt][ct], 0, 0, 0);
            }
    }

#pragma unroll
    for (int mt = 0; mt < 2; mt++)
#pragma unroll
        for (int ct = 0; ct < 4; ct++)
#pragma unroll
            for (int j = 0; j < 4; j++) {
                int rr = r0 + wid * 32 + mt * 16 + lg * 4 + j;
                if (rr >= M) continue;
                int c = ct * 16 + lr;
                Cf[(size_t)rr * OUT_C + c] = acc[mt][ct][j] + bias[c];
            }
}

// ---------------------------------------------------------------------------
// CSR aggregation: wave = node, 64 lanes x f16x2 = full 128-ch fp16 row
// (256 B) per instruction, unroll-16 (64 lines in flight per wave).
// out = relu(dis[node]*sum + bias) -> packed uint (uint2/lane, 512 B/wave).
// ---------------------------------------------------------------------------

__global__ __launch_bounds__(256) void aggregate_kernel(const _Float16* __restrict__ g,
                                                        const int* __restrict__ row_ptr,
                                                        const ushort* __restrict__ csr_src,
                                                        const float* __restrict__ dis,
                                                        const float* __restrict__ bias,
                                                        uint* __restrict__ hx) {
    const int wid = threadIdx.x >> 6;
    const int lane = threadIdx.x & 63;
    const int node = blockIdx.x * 4 + wid;
    if (node >= N_NODES) return;
    const int c2 = lane * 2;

    const int s0 = row_ptr[node];
    const int s1 = row_ptr[node + 1];

    float ax = 0.f, ay = 0.f;
    int e = s0;
    for (; e + 16 <= s1; e += 16) {
        int idx[16];
#pragma unroll
        for (int j = 0; j < 16; j++) idx[j] = csr_src[e + j];
        f16x2 v[16];
#pragma unroll
        for (int j = 0; j < 16; j++)
            v[j] = *(const f16x2*)&g[(size_t)idx[j] * HID_C + c2];
        float sx = 0.f, sy = 0.f;
#pragma unroll
        for (int j = 0; j < 16; j++) {
            sx += (float)v[j].x;
            sy += (float)v[j].y;
        }
        ax += sx;
        ay += sy;
    }
    for (; e + 4 <= s1; e += 4) {
        int idx[4];
#pragma unroll
        for (int j = 0; j < 4; j++) idx[j] = csr_src[e + j];
        f16x2 v[4];
#pragma unroll
        for (int j = 0; j < 4; j++)
            v[j] = *(const f16x2*)&g[(size_t)idx[j] * HID_C + c2];
        ax += ((float)v[0].x + (float)v[1].x) + ((float)v[2].x + (float)v[3].x);
        ay += ((float)v[0].y + (float)v[1].y) + ((float)v[2].y + (float)v[3].y);
    }
    for (; e < s1; e++) {
        int i0 = csr_src[e];
        f16x2 v0 = *(const f16x2*)&g[(size_t)i0 * HID_C + c2];
        ax += (float)v0.x;
        ay += (float)v0.y;
    }

    const float dn = dis[node];
    float2 bb = *(const float2*)&bias[c2];
    float vx = fmaxf(dn * ax + bb.x, 0.f);
    float vy = fmaxf(dn * ay + bb.y, 0.f);
    uint2 w;
    w.x = packhl(vx);
    w.y = packhl(vy);
    *(uint2*)&hx[(size_t)node * HID_C + c2] = w;
}

// ---------------------------------------------------------------------------
// Launch
// ---------------------------------------------------------------------------

extern "C" void kernel_launch(void* const* d_in, const int* in_sizes, int n_in,
                              void* d_out, int out_size, void* d_ws, size_t ws_size,
                              hipStream_t stream) {
    const float* x       = (const float*)d_in[0];
    const int*   eidx    = (const int*)d_in[1];
    const float* proj_W  = (const float*)d_in[2];
    const float* proj_b  = (const float*)d_in[3];
    const float* conv_W0 = (const float*)d_in[4];
    const float* conv_b0 = (const float*)d_in[5];
    const float* conv_W1 = (const float*)d_in[6];
    const float* conv_b1 = (const float*)d_in[7];
    const float* conv_W2 = (const float*)d_in[8];
    const float* conv_b2 = (const float*)d_in[9];
    const float* out_W   = (const float*)d_in[10];
    const float* out_b   = (const float*)d_in[11];
    float* out = (float*)d_out;

    const int* src = eidx;
    const int* dst = eidx + N_EDGES;

    char* ws = (char*)d_ws;
    size_t off = 0;
    auto carve = [&](size_t bytes) {
        void* p = ws + off;
        off += (bytes + 255) & ~(size_t)255;
        return p;
    };
    int*    row_ptr  = (int*)carve((N_NODES + 1) * sizeof(int));
    ushort* csr_src  = (ushort*)carve((size_t)N_TOT * sizeof(ushort));
    uint*   binned   = (uint*)carve((size_t)N_TOT * sizeof(uint));
    int*    binhist  = (int*)carve(N_BINS * sizeof(int));
    int*    bin_base = (int*)carve((N_BINS + 1) * sizeof(int));
    int*    bincur   = (int*)carve(N_BINS * sizeof(int));
    float*  dis      = (float*)carve(N_NODES * sizeof(float));
    ushort* projPh = (ushort*)carve((size_t)IN_C * HID_C * sizeof(ushort));
    ushort* projPl = (ushort*)carve((size_t)IN_C * HID_C * sizeof(ushort));
    ushort* convPh[3], *convPl[3];
    for (int l = 0; l < 3; l++) {
        convPh[l] = (ushort*)carve((size_t)HID_C * HID_C * sizeof(ushort));
        convPl[l] = (ushort*)carve((size_t)HID_C * HID_C * sizeof(ushort));
    }
    ushort* outPh = (ushort*)carve((size_t)HID_C * OUT_C * sizeof(ushort));
    ushort* outPl = (ushort*)carve((size_t)HID_C * OUT_C * sizeof(ushort));
    uint*   hx = (uint*)carve((size_t)N_NODES * HID_C * sizeof(uint));
    _Float16* g = (_Float16*)carve((size_t)N_NODES * HID_C * sizeof(_Float16));

    // Graph preprocessing (bin-centric)
    zero_binhist_kernel<<<(N_BINS + 255) / 256, 256, 0, stream>>>(binhist);
    bin_hist_kernel<<<196, 256, 0, stream>>>(dst, binhist);
    bin_scan_kernel<<<1, 512, 0, stream>>>(binhist, bin_base, bincur, row_ptr);
    bin_scatter_kernel<<<RB_GRID, RB_BLOCK, 0, stream>>>(
        src, dst, bin_base, bincur, binned);
    csr_build_kernel<<<N_BINS, 256, 0, stream>>>(
        binned, bin_base, row_ptr, dis, csr_src);

    // Weight packing: one launch for all 5 matrices
    pack_all_kernel<<<176, 64, 0, stream>>>(proj_W, conv_W0, conv_W1, conv_W2, out_W,
                                            projPh, projPl,
                                            convPh[0], convPl[0],
                                            convPh[1], convPl[1],
                                            convPh[2], convPl[2],
                                            outPh, outPl);

    const int grid_n128 = (N_NODES + 63) / 64;    // 782
    const int agg_grid  = (N_NODES + 3) / 4;      // 12500

    // Projection: hx = pack(x @ proj_W + proj_b)  (r16/r19 register path)
    proj_gemm_kernel<<<grid_n128, 256, 0, stream>>>(
        x, projPh, projPl, proj_b, hx, N_NODES);

    // 3 GCN layers (conv = LDS-staged GEMM)
    ushort* Wh_[3] = {convPh[0], convPh[1], convPh[2]};
    ushort* Wl_[3] = {convPl[0], convPl[1], convPl[2]};
    const float* bs_[3] = {conv_b0, conv_b1, conv_b2};
    for (int l = 0; l < 3; l++) {
        conv_gemm_lds_kernel<<<grid_n128, 256, 0, stream>>>(
            hx, Wh_[l], Wl_[l], dis, g, N_NODES);
        aggregate_kernel<<<agg_grid, 256, 0, stream>>>(
            g, row_ptr, csr_src, dis, bs_[l], hx);
    }

    // Output: out = h @ out_W + out_b (fp32, LDS-staged)
    out_gemm_lds_kernel<<<grid_n128, 128, 0, stream>>>(
        hx, outPh, outPl, out_b, out, N_NODES);
}